// Round 1
// 914.600 us; speedup vs baseline: 1.0018x; 1.0018x over previous
//
#include <hip/hip_runtime.h>
#include <stdint.h>

#define D_MODEL 1024
#define D_FF    4096
#define NE      8
#define T_TOK   4096
#define R_TOT   8192   // T_TOK * TOP_K, always exact (top-2 of 8 distinct)

typedef float f32x4 __attribute__((ext_vector_type(4)));
typedef __bf16 bf16x8 __attribute__((ext_vector_type(8)));
typedef unsigned short ushort_t;

__device__ __forceinline__ ushort_t f2bf(float f) {
    unsigned int u = __float_as_uint(f);
    u += 0x7FFFu + ((u >> 16) & 1u);   // round-to-nearest-even
    return (ushort_t)(u >> 16);
}

// async global->LDS, 16B per lane. Pass a WAVE-UNIFORM lds base; HW adds lane*16.
__device__ __forceinline__ void async16(const void* g, const void* l) {
    __builtin_amdgcn_global_load_lds(
        (const __attribute__((address_space(1))) unsigned int*)(uintptr_t)g,
        (__attribute__((address_space(3))) unsigned int*)(uintptr_t)l,
        16, 0, 0);
}

// ---------------- gate: one wave per token ----------------
__global__ __launch_bounds__(256) void k_gate(
    const float* __restrict__ x, const float* __restrict__ Wg, const float* __restrict__ bg,
    int* __restrict__ topi, float* __restrict__ topw, int* __restrict__ counts)
{
    int wave = threadIdx.x >> 6, lane = threadIdx.x & 63;
    int t = blockIdx.x * 4 + wave;
    const float* xr = x + (size_t)t * D_MODEL;
    float acc[NE];
#pragma unroll
    for (int e = 0; e < NE; ++e) acc[e] = 0.f;
#pragma unroll
    for (int i = 0; i < D_MODEL / 64; ++i) {
        int k = i * 64 + lane;
        float xv = xr[k];
        const float4* wgp = (const float4*)(Wg + (size_t)k * NE);
        float4 w0 = wgp[0], w1 = wgp[1];
        acc[0] += xv * w0.x; acc[1] += xv * w0.y; acc[2] += xv * w0.z; acc[3] += xv * w0.w;
        acc[4] += xv * w1.x; acc[5] += xv * w1.y; acc[6] += xv * w1.z; acc[7] += xv * w1.w;
    }
#pragma unroll
    for (int off = 32; off >= 1; off >>= 1)
#pragma unroll
        for (int e = 0; e < NE; ++e) acc[e] += __shfl_down(acc[e], off, 64);
    if (lane == 0) {
        float l[NE], m = -1e30f;
#pragma unroll
        for (int e = 0; e < NE; ++e) { l[e] = acc[e] + bg[e]; m = fmaxf(m, l[e]); }
        float p[NE], Z = 0.f;
#pragma unroll
        for (int e = 0; e < NE; ++e) { p[e] = __expf(l[e] - m); Z += p[e]; }
        float invZ = 1.f / Z;
        int i0 = 0; float v0 = -1.f;
#pragma unroll
        for (int e = 0; e < NE; ++e) { p[e] *= invZ; if (p[e] > v0) { v0 = p[e]; i0 = e; } }
        int i1 = 0; float v1 = -1.f;
#pragma unroll
        for (int e = 0; e < NE; ++e) { if (e != i0 && p[e] > v1) { v1 = p[e]; i1 = e; } }
        float denom = 1.f / (v0 + v1 + 1e-6f);
        topi[t * 2 + 0] = i0; topi[t * 2 + 1] = i1;
        topw[t * 2 + 0] = v0 * denom; topw[t * 2 + 1] = v1 * denom;
        atomicAdd(&counts[i0], 1); atomicAdd(&counts[i1], 1);
    }
}

// ---------------- tiny scan ----------------
__global__ void k_scan(const int* __restrict__ counts, int* __restrict__ offsets,
                       int* __restrict__ cursors)
{
    if (threadIdx.x == 0) {
        int acc = 0;
        for (int e = 0; e < NE; ++e) { offsets[e] = acc; cursors[e] = acc; acc += counts[e]; }
    }
}

// ---------------- scatter tokens into expert buckets ----------------
__global__ __launch_bounds__(256) void k_scatter(
    const int* __restrict__ topi, const float* __restrict__ topw,
    int* __restrict__ cursors, int* __restrict__ btok, float* __restrict__ bw)
{
    int t = blockIdx.x * 256 + threadIdx.x;
#pragma unroll
    for (int k = 0; k < 2; ++k) {
        int e = topi[t * 2 + k];
        int p = atomicAdd(&cursors[e], 1);
        btok[p] = t;
        bw[p] = topw[t * 2 + k];
    }
}

// ---------------- gather x rows (bucket order) + fp32->bf16 ----------------
__global__ __launch_bounds__(256) void k_gather(
    const float* __restrict__ x, const int* __restrict__ btok, ushort_t* __restrict__ Xg)
{
    int i = blockIdx.x;
    int t = btok[i];
    float4 v = ((const float4*)(x + (size_t)t * D_MODEL))[threadIdx.x];
    ushort4 o;
    o.x = f2bf(v.x); o.y = f2bf(v.y); o.z = f2bf(v.z); o.w = f2bf(v.w);
    ((ushort4*)(Xg + (size_t)i * D_MODEL))[threadIdx.x] = o;
}

// ---------------- weight transpose+convert: W[e][K][N] fp32 -> Wt[e][N][K] bf16 ----------------
__global__ __launch_bounds__(256) void k_transpose(
    const float* __restrict__ W, ushort_t* __restrict__ Wt, int K, int N)
{
    __shared__ ushort_t tile[64 * 72];
    int e = blockIdx.z;
    const float* We = W + (size_t)e * K * N;
    ushort_t* Wte = Wt + (size_t)e * K * N;
    int nb = blockIdx.x * 64, kb = blockIdx.y * 64;
    int tn4 = (threadIdx.x & 15) * 4;
    int tk = threadIdx.x >> 4;
#pragma unroll
    for (int r = 0; r < 4; ++r) {
        int k = r * 16 + tk;
        float4 v = *(const float4*)(We + (size_t)(kb + k) * N + nb + tn4);
        tile[(tn4 + 0) * 72 + k] = f2bf(v.x);
        tile[(tn4 + 1) * 72 + k] = f2bf(v.y);
        tile[(tn4 + 2) * 72 + k] = f2bf(v.z);
        tile[(tn4 + 3) * 72 + k] = f2bf(v.w);
    }
    __syncthreads();
#pragma unroll
    for (int c = 0; c < 4; ++c) {
        int chunk = c * 256 + threadIdx.x;
        int n = chunk >> 4, kc = (chunk & 15) * 4;
        ushort4 o = *(const ushort4*)&tile[n * 72 + kc];
        *(ushort4*)(Wte + (size_t)(nb + n) * K + kb + kc) = o;
    }
}

// =====================================================================
// Grouped GEMMs, 8-wave 256x128 tiles, double-buffered LDS with COUNTED
// vmcnt (T3+T4) + setprio around MFMA cluster (T5) + XCD-aware swizzle (T1).
//
// LDS tile layout (per K-step of 64): row = 128 B = 8 chunks of 16 B.
// Chunk c of row r stored at slot c ^ (r & 7) (T2 bank-conflict swizzle).
// Swizzle applied on the GLOBAL address of global_load_lds (LDS side is
// HW-fixed wave base + lane*16) and un-done on the ds_read side.
//
// Schedule per K-tile t (buffers p = t&1):
//   issue 8 (resp 6) global_load_lds for tile t+1 -> buf[p^1]
//   s_waitcnt vmcnt(8|6)      // waits ONLY on tile t's loads; t+1 stays in flight
//   s_barrier                 // tile t visible to all waves
//   ds_read frags; setprio(1); 32 MFMA; setprio(0)   (x2 kk halves)
//   s_barrier                 // all waves done reading buf[p]
// Loads are never drained to 0 inside the loop (m218 mechanism).
// =====================================================================

// ---------------- grouped GEMM1: H = silu(Xg@W1 + b1) * (Xg@W3 + b3) ----------------
__global__ __launch_bounds__(512, 2) void k_gemm1(
    const ushort_t* __restrict__ Xg, const ushort_t* __restrict__ W1t,
    const ushort_t* __restrict__ W3t,
    const float* __restrict__ b1, const float* __restrict__ b3,
    const int* __restrict__ counts, const int* __restrict__ offsets,
    ushort_t* __restrict__ H)
{
    __shared__ __align__(16) ushort_t sA [2][256 * 64];   // 64 KB
    __shared__ __align__(16) ushort_t sB1[2][128 * 64];   // 32 KB
    __shared__ __align__(16) ushort_t sB3[2][128 * 64];   // 32 KB

    // Bijective XCD swizzle: grid.x = 40 = 8 XCDs * 5, and 40 % 8 == 0 so the
    // hw XCD of a block depends only on bx&7. Logical row-tiles [5k,5k+5)
    // land on XCD k -> B panels shared within an XCD's L2; A panels shared
    // across all blockIdx.y on the same XCD.
    int bx = blockIdx.x;
    int lx = (bx & 7) * 5 + (bx >> 3);

    int tm = lx, e = 0, cnt = 0;
    for (; e < NE; ++e) {
        cnt = counts[e];
        int nt = (cnt + 255) >> 8;
        if (tm < nt) break;
        tm -= nt;
    }
    if (e >= NE) return;
    int row0 = offsets[e] + tm * 256;
    int rows_left = cnt - tm * 256;

    int tile_n = blockIdx.y * 128;
    int tid = threadIdx.x, wave = tid >> 6, lane = tid & 63;
    int wm = (wave >> 1) * 64, wn = (wave & 1) * 64;   // 4M x 2N wave grid
    int col = lane & 15, quad = lane >> 4;

    const ushort_t* W1e = W1t + (size_t)e * D_FF * D_MODEL;
    const ushort_t* W3e = W3t + (size_t)e * D_FF * D_MODEL;

    // staging source pointers (pre-swizzled global) + uniform lds bases
    const ushort_t* gA[4]; const ushort_t* gB1[2]; const ushort_t* gB3[2];
    unsigned offA[4], offB[2];
#pragma unroll
    for (int s = 0; s < 4; ++s) {
        int q = (wave * 4 + s) * 64 + lane;          // 16B-chunk index in 256x64 tile
        int r = q >> 3;
        int cg = ((q & 7) ^ (r & 7)) * 8;
        gA[s]  = Xg + (size_t)(row0 + r) * D_MODEL + cg;
        offA[s] = (unsigned)(wave * 4 + s) * 512;    // elements (1 KB per instr)
    }
#pragma unroll
    for (int s = 0; s < 2; ++s) {
        int q = (wave * 2 + s) * 64 + lane;          // 16B-chunk index in 128x64 tile
        int r = q >> 3;
        int cg = ((q & 7) ^ (r & 7)) * 8;
        gB1[s] = W1e + (size_t)(tile_n + r) * D_MODEL + cg;
        gB3[s] = W3e + (size_t)(tile_n + r) * D_MODEL + cg;
        offB[s] = (unsigned)(wave * 2 + s) * 512;
    }

    // frag lds offsets: row*64 + swz, toggle ^32 for kk=32
    int swz = (quad ^ (col & 7)) * 8;
    unsigned fA[4], fB[4];
#pragma unroll
    for (int i = 0; i < 4; ++i) {
        fA[i] = (unsigned)(wm + i * 16 + col) * 64 + swz;
        fB[i] = (unsigned)(wn + i * 16 + col) * 64 + swz;
    }

    f32x4 acc1[4][4], acc3[4][4];
#pragma unroll
    for (int i = 0; i < 4; ++i)
#pragma unroll
        for (int j = 0; j < 4; ++j) {
            acc1[i][j] = (f32x4){0.f, 0.f, 0.f, 0.f};
            acc3[i][j] = (f32x4){0.f, 0.f, 0.f, 0.f};
        }

#define STAGE1(p, k0)                                                          \
    do {                                                                       \
        _Pragma("unroll")                                                      \
        for (int s_ = 0; s_ < 4; ++s_) async16(gA[s_] + (k0), &sA[p][offA[s_]]); \
        _Pragma("unroll")                                                      \
        for (int s_ = 0; s_ < 2; ++s_) {                                       \
            async16(gB1[s_] + (k0), &sB1[p][offB[s_]]);                        \
            async16(gB3[s_] + (k0), &sB3[p][offB[s_]]);                        \
        }                                                                      \
    } while (0)

    STAGE1(0, 0);
    for (int t = 0; t < D_MODEL / 64; ++t) {
        int p = t & 1;
        if (t < D_MODEL / 64 - 1) {
            STAGE1(p ^ 1, (t + 1) * 64);
            asm volatile("s_waitcnt vmcnt(8)" ::: "memory");
        } else {
            asm volatile("s_waitcnt vmcnt(0)" ::: "memory");
        }
        __builtin_amdgcn_s_barrier();
        asm volatile("" ::: "memory");
#pragma unroll
        for (int kk = 0; kk < 2; ++kk) {
            unsigned kx = kk * 32;
            bf16x8 a[4], u1[4], u3[4];
#pragma unroll
            for (int j = 0; j < 4; ++j) {
                u1[j] = *(const bf16x8*)(&sB1[p][fB[j] ^ kx]);
                u3[j] = *(const bf16x8*)(&sB3[p][fB[j] ^ kx]);
            }
#pragma unroll
            for (int i = 0; i < 4; ++i) a[i] = *(const bf16x8*)(&sA[p][fA[i] ^ kx]);
            __builtin_amdgcn_s_setprio(1);
#pragma unroll
            for (int i = 0; i < 4; ++i)
#pragma unroll
                for (int j = 0; j < 4; ++j) {
                    acc1[i][j] = __builtin_amdgcn_mfma_f32_16x16x32_bf16(a[i], u1[j], acc1[i][j], 0, 0, 0);
                    acc3[i][j] = __builtin_amdgcn_mfma_f32_16x16x32_bf16(a[i], u3[j], acc3[i][j], 0, 0, 0);
                }
            __builtin_amdgcn_s_setprio(0);
        }
        asm volatile("" ::: "memory");
        __builtin_amdgcn_s_barrier();
        asm volatile("" ::: "memory");
    }
#undef STAGE1

#pragma unroll
    for (int j = 0; j < 4; ++j) {
        int n = tile_n + wn + j * 16 + col;
        float bias1 = b1[e * D_FF + n];
        float bias3 = b3[e * D_FF + n];
#pragma unroll
        for (int i = 0; i < 4; ++i) {
            int rbase = wm + i * 16 + quad * 4;
#pragma unroll
            for (int r = 0; r < 4; ++r) {
                int row = rbase + r;
                if (row < rows_left) {
                    float h1 = acc1[i][j][r] + bias1;
                    float h3 = acc3[i][j][r] + bias3;
                    float s = h1 / (1.f + __expf(-h1));   // silu
                    H[(size_t)(row0 + row) * D_FF + n] = f2bf(s * h3);
                }
            }
        }
    }
}

// ---------------- grouped GEMM2: out[tok] += w * (H @ W2 + b2) ----------------
__global__ __launch_bounds__(512, 2) void k_gemm2(
    const ushort_t* __restrict__ H, const ushort_t* __restrict__ W2t,
    const float* __restrict__ b2,
    const int* __restrict__ counts, const int* __restrict__ offsets,
    const int* __restrict__ btok, const float* __restrict__ bw,
    float* __restrict__ out)
{
    __shared__ __align__(16) ushort_t sA[2][256 * 64];   // 64 KB
    __shared__ __align__(16) ushort_t sB[2][128 * 64];   // 32 KB

    int bx = blockIdx.x;
    int lx = (bx & 7) * 5 + (bx >> 3);

    int tm = lx, e = 0, cnt = 0;
    for (; e < NE; ++e) {
        cnt = counts[e];
        int nt = (cnt + 255) >> 8;
        if (tm < nt) break;
        tm -= nt;
    }
    if (e >= NE) return;
    int row0 = offsets[e] + tm * 256;
    int rows_left = cnt - tm * 256;

    int tile_n = blockIdx.y * 128;
    int tid = threadIdx.x, wave = tid >> 6, lane = tid & 63;
    int wm = (wave >> 1) * 64, wn = (wave & 1) * 64;
    int col = lane & 15, quad = lane >> 4;

    const ushort_t* W2e = W2t + (size_t)e * D_MODEL * D_FF;

    const ushort_t* gA[4]; const ushort_t* gB[2];
    unsigned offA[4], offB[2];
#pragma unroll
    for (int s = 0; s < 4; ++s) {
        int q = (wave * 4 + s) * 64 + lane;
        int r = q >> 3;
        int cg = ((q & 7) ^ (r & 7)) * 8;
        gA[s] = H + (size_t)(row0 + r) * D_FF + cg;
        offA[s] = (unsigned)(wave * 4 + s) * 512;
    }
#pragma unroll
    for (int s = 0; s < 2; ++s) {
        int q = (wave * 2 + s) * 64 + lane;
        int r = q >> 3;
        int cg = ((q & 7) ^ (r & 7)) * 8;
        gB[s] = W2e + (size_t)(tile_n + r) * D_FF + cg;
        offB[s] = (unsigned)(wave * 2 + s) * 512;
    }

    int swz = (quad ^ (col & 7)) * 8;
    unsigned fA[4], fB[4];
#pragma unroll
    for (int i = 0; i < 4; ++i) {
        fA[i] = (unsigned)(wm + i * 16 + col) * 64 + swz;
        fB[i] = (unsigned)(wn + i * 16 + col) * 64 + swz;
    }

    f32x4 acc[4][4];
#pragma unroll
    for (int i = 0; i < 4; ++i)
#pragma unroll
        for (int j = 0; j < 4; ++j) acc[i][j] = (f32x4){0.f, 0.f, 0.f, 0.f};

#define STAGE2(p, k0)                                                          \
    do {                                                                       \
        _Pragma("unroll")                                                      \
        for (int s_ = 0; s_ < 4; ++s_) async16(gA[s_] + (k0), &sA[p][offA[s_]]); \
        _Pragma("unroll")                                                      \
        for (int s_ = 0; s_ < 2; ++s_) async16(gB[s_] + (k0), &sB[p][offB[s_]]); \
    } while (0)

    STAGE2(0, 0);
    for (int t = 0; t < D_FF / 64; ++t) {
        int p = t & 1;
        if (t < D_FF / 64 - 1) {
            STAGE2(p ^ 1, (t + 1) * 64);
            asm volatile("s_waitcnt vmcnt(6)" ::: "memory");
        } else {
            asm volatile("s_waitcnt vmcnt(0)" ::: "memory");
        }
        __builtin_amdgcn_s_barrier();
        asm volatile("" ::: "memory");
#pragma unroll
        for (int kk = 0; kk < 2; ++kk) {
            unsigned kx = kk * 32;
            bf16x8 a[4], b[4];
#pragma unroll
            for (int j = 0; j < 4; ++j) b[j] = *(const bf16x8*)(&sB[p][fB[j] ^ kx]);
#pragma unroll
            for (int i = 0; i < 4; ++i) a[i] = *(const bf16x8*)(&sA[p][fA[i] ^ kx]);
            __builtin_amdgcn_s_setprio(1);
#pragma unroll
            for (int i = 0; i < 4; ++i)
#pragma unroll
                for (int j = 0; j < 4; ++j)
                    acc[i][j] = __builtin_amdgcn_mfma_f32_16x16x32_bf16(a[i], b[j], acc[i][j], 0, 0, 0);
            __builtin_amdgcn_s_setprio(0);
        }
        asm volatile("" ::: "memory");
        __builtin_amdgcn_s_barrier();
        asm volatile("" ::: "memory");
    }
#undef STAGE2

    float bias[4];
#pragma unroll
    for (int j = 0; j < 4; ++j) bias[j] = b2[e * D_MODEL + tile_n + wn + j * 16 + col];

#pragma unroll
    for (int i = 0; i < 4; ++i) {
        int rbase = wm + i * 16 + quad * 4;
#pragma unroll
        for (int r = 0; r < 4; ++r) {
            int row = rbase + r;
            if (row < rows_left) {
                int g_r = row0 + row;
                int t = btok[g_r];
                float w = bw[g_r];
                float* orow = out + (size_t)t * D_MODEL + tile_n + wn + col;
#pragma unroll
                for (int j = 0; j < 4; ++j)
                    atomicAdd(orow + j * 16, w * (acc[i][j][r] + bias[j]));
            }
        }
    }
}

extern "C" void kernel_launch(void* const* d_in, const int* in_sizes, int n_in,
                              void* d_out, int out_size, void* d_ws, size_t ws_size,
                              hipStream_t stream)
{
    const float* x  = (const float*)d_in[0];
    const float* Wg = (const float*)d_in[1];
    const float* bg = (const float*)d_in[2];
    const float* W1 = (const float*)d_in[3];
    const float* b1 = (const float*)d_in[4];
    const float* W3 = (const float*)d_in[5];
    const float* b3 = (const float*)d_in[6];
    const float* W2 = (const float*)d_in[7];
    const float* b2 = (const float*)d_in[8];
    float* out = (float*)d_out;

    char* ws = (char*)d_ws;
    int*   counts  = (int*)(ws + 0);
    int*   cursors = (int*)(ws + 32);
    int*   offsets = (int*)(ws + 64);
    int*   topi    = (int*)(ws + 256);
    float* topw    = (float*)(ws + 256 + 32768);
    int*   btok    = (int*)(ws + 256 + 65536);
    float* bw      = (float*)(ws + 256 + 98304);
    char* p = ws + 131328;
    ushort_t* Xg  = (ushort_t*)p;  p += (size_t)R_TOT * D_MODEL * 2;      // 16.78 MB
    ushort_t* Hb  = (ushort_t*)p;  p += (size_t)R_TOT * D_FF * 2;         // 67.1 MB
    ushort_t* W1t = (ushort_t*)p;  p += (size_t)NE * D_FF * D_MODEL * 2;  // 67.1 MB
    ushort_t* W3t = (ushort_t*)p;  p += (size_t)NE * D_FF * D_MODEL * 2;  // 67.1 MB
    ushort_t* W2t = (ushort_t*)p;                                          // 67.1 MB

    hipMemsetAsync(ws, 0, 64, stream);                       // counts + cursors
    hipMemsetAsync(d_out, 0, (size_t)out_size * 4, stream);  // atomics accumulate into out

    k_gate<<<dim3(T_TOK / 4), dim3(256), 0, stream>>>(x, Wg, bg, topi, topw, counts);
    k_scan<<<dim3(1), dim3(64), 0, stream>>>(counts, offsets, cursors);
    k_scatter<<<dim3(T_TOK / 256), dim3(256), 0, stream>>>(topi, topw, cursors, btok, bw);
    k_gather<<<dim3(R_TOT), dim3(256), 0, stream>>>(x, btok, Xg);
    k_transpose<<<dim3(D_FF / 64, D_MODEL / 64, NE), dim3(256), 0, stream>>>(W1, W1t, D_MODEL, D_FF);
    k_transpose<<<dim3(D_FF / 64, D_MODEL / 64, NE), dim3(256), 0, stream>>>(W3, W3t, D_MODEL, D_FF);
    k_transpose<<<dim3(D_MODEL / 64, D_FF / 64, NE), dim3(256), 0, stream>>>(W2, W2t, D_FF, D_MODEL);
    // grid.x = 40 = max row-tiles (sum ceil(cnt_e/256) <= 39) and = 8 XCDs * 5 for the swizzle
    k_gemm1<<<dim3(40, D_FF / 128), dim3(512), 0, stream>>>(Xg, W1t, W3t, b1, b3, counts, offsets, Hb);
    k_gemm2<<<dim3(40, D_MODEL / 128), dim3(512), 0, stream>>>(Hb, W2t, b2, counts, offsets, btok, bw, out);
}

// Round 2
// 894.239 us; speedup vs baseline: 1.0246x; 1.0228x over previous
//
#include <hip/hip_runtime.h>
#include <stdint.h>

#define D_MODEL 1024
#define D_FF    4096
#define NE      8
#define T_TOK   4096
#define R_TOT   8192   // T_TOK * TOP_K, always exact (top-2 of 8 distinct)

typedef float f32x4 __attribute__((ext_vector_type(4)));
typedef __bf16 bf16x8 __attribute__((ext_vector_type(8)));
typedef unsigned short ushort_t;

__device__ __forceinline__ ushort_t f2bf(float f) {
    unsigned int u = __float_as_uint(f);
    u += 0x7FFFu + ((u >> 16) & 1u);   // round-to-nearest-even
    return (ushort_t)(u >> 16);
}

// async global->LDS, 16B per lane. Pass a WAVE-UNIFORM lds base; HW adds lane*16.
__device__ __forceinline__ void async16(const void* g, const void* l) {
    __builtin_amdgcn_global_load_lds(
        (const __attribute__((address_space(1))) unsigned int*)(uintptr_t)g,
        (__attribute__((address_space(3))) unsigned int*)(uintptr_t)l,
        16, 0, 0);
}

#define FENCE() asm volatile("" ::: "memory")

// ---------------- gate: one wave per token ----------------
__global__ __launch_bounds__(256) void k_gate(
    const float* __restrict__ x, const float* __restrict__ Wg, const float* __restrict__ bg,
    int* __restrict__ topi, float* __restrict__ topw, int* __restrict__ counts)
{
    int wave = threadIdx.x >> 6, lane = threadIdx.x & 63;
    int t = blockIdx.x * 4 + wave;
    const float* xr = x + (size_t)t * D_MODEL;
    float acc[NE];
#pragma unroll
    for (int e = 0; e < NE; ++e) acc[e] = 0.f;
#pragma unroll
    for (int i = 0; i < D_MODEL / 64; ++i) {
        int k = i * 64 + lane;
        float xv = xr[k];
        const float4* wgp = (const float4*)(Wg + (size_t)k * NE);
        float4 w0 = wgp[0], w1 = wgp[1];
        acc[0] += xv * w0.x; acc[1] += xv * w0.y; acc[2] += xv * w0.z; acc[3] += xv * w0.w;
        acc[4] += xv * w1.x; acc[5] += xv * w1.y; acc[6] += xv * w1.z; acc[7] += xv * w1.w;
    }
#pragma unroll
    for (int off = 32; off >= 1; off >>= 1)
#pragma unroll
        for (int e = 0; e < NE; ++e) acc[e] += __shfl_down(acc[e], off, 64);
    if (lane == 0) {
        float l[NE], m = -1e30f;
#pragma unroll
        for (int e = 0; e < NE; ++e) { l[e] = acc[e] + bg[e]; m = fmaxf(m, l[e]); }
        float p[NE], Z = 0.f;
#pragma unroll
        for (int e = 0; e < NE; ++e) { p[e] = __expf(l[e] - m); Z += p[e]; }
        float invZ = 1.f / Z;
        int i0 = 0; float v0 = -1.f;
#pragma unroll
        for (int e = 0; e < NE; ++e) { p[e] *= invZ; if (p[e] > v0) { v0 = p[e]; i0 = e; } }
        int i1 = 0; float v1 = -1.f;
#pragma unroll
        for (int e = 0; e < NE; ++e) { if (e != i0 && p[e] > v1) { v1 = p[e]; i1 = e; } }
        float denom = 1.f / (v0 + v1 + 1e-6f);
        topi[t * 2 + 0] = i0; topi[t * 2 + 1] = i1;
        topw[t * 2 + 0] = v0 * denom; topw[t * 2 + 1] = v1 * denom;
        atomicAdd(&counts[i0], 1); atomicAdd(&counts[i1], 1);
    }
}

// ---------------- tiny scan ----------------
__global__ void k_scan(const int* __restrict__ counts, int* __restrict__ offsets,
                       int* __restrict__ cursors)
{
    if (threadIdx.x == 0) {
        int acc = 0;
        for (int e = 0; e < NE; ++e) { offsets[e] = acc; cursors[e] = acc; acc += counts[e]; }
    }
}

// ---------------- scatter tokens into expert buckets ----------------
// Also writes the bucket position back into topi (repurposed as pos map for k_combine).
__global__ __launch_bounds__(256) void k_scatter(
    const int* __restrict__ topi_in, const float* __restrict__ topw,
    int* __restrict__ cursors, int* __restrict__ btok, float* __restrict__ bw)
{
    int t = blockIdx.x * 256 + threadIdx.x;
    int* topi = (int*)topi_in;
#pragma unroll
    for (int k = 0; k < 2; ++k) {
        int e = topi[t * 2 + k];
        int p = atomicAdd(&cursors[e], 1);
        btok[p] = t;
        bw[p] = topw[t * 2 + k];
        topi[t * 2 + k] = p;     // pos map: token -> bucket row
    }
}

// ---------------- gather x rows (bucket order) + fp32->bf16 ----------------
__global__ __launch_bounds__(256) void k_gather(
    const float* __restrict__ x, const int* __restrict__ btok, ushort_t* __restrict__ Xg)
{
    int i = blockIdx.x;
    int t = btok[i];
    float4 v = ((const float4*)(x + (size_t)t * D_MODEL))[threadIdx.x];
    ushort4 o;
    o.x = f2bf(v.x); o.y = f2bf(v.y); o.z = f2bf(v.z); o.w = f2bf(v.w);
    ((ushort4*)(Xg + (size_t)i * D_MODEL))[threadIdx.x] = o;
}

// ---------------- weight transpose+convert: W[e][K][N] fp32 -> Wt[e][N][K] bf16 ----------------
__global__ __launch_bounds__(256) void k_transpose(
    const float* __restrict__ W, ushort_t* __restrict__ Wt, int K, int N)
{
    __shared__ ushort_t tile[64 * 72];
    int e = blockIdx.z;
    const float* We = W + (size_t)e * K * N;
    ushort_t* Wte = Wt + (size_t)e * K * N;
    int nb = blockIdx.x * 64, kb = blockIdx.y * 64;
    int tn4 = (threadIdx.x & 15) * 4;
    int tk = threadIdx.x >> 4;
#pragma unroll
    for (int r = 0; r < 4; ++r) {
        int k = r * 16 + tk;
        float4 v = *(const float4*)(We + (size_t)(kb + k) * N + nb + tn4);
        tile[(tn4 + 0) * 72 + k] = f2bf(v.x);
        tile[(tn4 + 1) * 72 + k] = f2bf(v.y);
        tile[(tn4 + 2) * 72 + k] = f2bf(v.z);
        tile[(tn4 + 3) * 72 + k] = f2bf(v.w);
    }
    __syncthreads();
#pragma unroll
    for (int c = 0; c < 4; ++c) {
        int chunk = c * 256 + threadIdx.x;
        int n = chunk >> 4, kc = (chunk & 15) * 4;
        ushort4 o = *(const ushort4*)&tile[n * 72 + kc];
        *(ushort4*)(Wte + (size_t)(nb + n) * K + kb + kc) = o;
    }
}

// =====================================================================
// Grouped GEMMs, 8-wave 256x128 tiles, fine-phase interleave (T3+T4):
// each phase = {ds_read subtile; issue 2-3 global_load_lds; counted vmcnt;
// s_barrier; setprio(1); 16 MFMA; setprio(0); s_barrier}. Loads are never
// drained to 0 mid-loop; a vmcnt always precedes >=1 barrier before the
// protected buffer is read (cross-wave visibility rule).
// LDS swizzle (T2) and bijective XCD swizzle (T1) carried over from R1.
// =====================================================================

// ---------------- grouped GEMM1: H = silu(Xg@W1 + b1) * (Xg@W3 + b3) ----------------
__global__ __launch_bounds__(512, 2) void k_gemm1(
    const ushort_t* __restrict__ Xg, const ushort_t* __restrict__ W1t,
    const ushort_t* __restrict__ W3t,
    const float* __restrict__ b1, const float* __restrict__ b3,
    const int* __restrict__ counts, const int* __restrict__ offsets,
    ushort_t* __restrict__ H)
{
    __shared__ __align__(16) ushort_t sA [2][256 * 64];   // 64 KB
    __shared__ __align__(16) ushort_t sB1[2][128 * 64];   // 32 KB
    __shared__ __align__(16) ushort_t sB3[2][128 * 64];   // 32 KB

    int bx = blockIdx.x;
    int lx = (bx & 7) * 5 + (bx >> 3);     // bijective: 40 = 8 XCD * 5

    int tm = lx, e = 0, cnt = 0;
    for (; e < NE; ++e) {
        cnt = counts[e];
        int nt = (cnt + 255) >> 8;
        if (tm < nt) break;
        tm -= nt;
    }
    if (e >= NE) return;
    int row0 = offsets[e] + tm * 256;
    int rows_left = cnt - tm * 256;

    int tile_n = blockIdx.y * 128;
    int tid = threadIdx.x, wave = tid >> 6, lane = tid & 63;
    int wm = (wave >> 1) * 64, wn = (wave & 1) * 64;   // 4M x 2N wave grid
    int col = lane & 15, quad = lane >> 4;

    const ushort_t* W1e = W1t + (size_t)e * D_FF * D_MODEL;
    const ushort_t* W3e = W3t + (size_t)e * D_FF * D_MODEL;

    const ushort_t* gA[4]; const ushort_t* gB1[2]; const ushort_t* gB3[2];
    unsigned offA[4], offB[2];
#pragma unroll
    for (int s = 0; s < 4; ++s) {
        int q = (wave * 4 + s) * 64 + lane;          // 16B-chunk index in 256x64 tile
        int r = q >> 3;
        int cg = ((q & 7) ^ (r & 7)) * 8;
        gA[s]  = Xg + (size_t)(row0 + r) * D_MODEL + cg;
        offA[s] = (unsigned)(wave * 4 + s) * 512;
    }
#pragma unroll
    for (int s = 0; s < 2; ++s) {
        int q = (wave * 2 + s) * 64 + lane;          // 16B-chunk index in 128x64 tile
        int r = q >> 3;
        int cg = ((q & 7) ^ (r & 7)) * 8;
        gB1[s] = W1e + (size_t)(tile_n + r) * D_MODEL + cg;
        gB3[s] = W3e + (size_t)(tile_n + r) * D_MODEL + cg;
        offB[s] = (unsigned)(wave * 2 + s) * 512;
    }

    int swz = (quad ^ (col & 7)) * 8;
    unsigned fA[4], fB[4];
#pragma unroll
    for (int i = 0; i < 4; ++i) {
        fA[i] = (unsigned)(wm + i * 16 + col) * 64 + swz;
        fB[i] = (unsigned)(wn + i * 16 + col) * 64 + swz;
    }

    f32x4 acc1[4][4], acc3[4][4];
#pragma unroll
    for (int i = 0; i < 4; ++i)
#pragma unroll
        for (int j = 0; j < 4; ++j) {
            acc1[i][j] = (f32x4){0.f, 0.f, 0.f, 0.f};
            acc3[i][j] = (f32x4){0.f, 0.f, 0.f, 0.f};
        }

    // prologue: tile 0 -> buf 0 (units: A0..3, B1x2, B3x2)
#pragma unroll
    for (int s = 0; s < 4; ++s) async16(gA[s], &sA[0][offA[s]]);
#pragma unroll
    for (int s = 0; s < 2; ++s) async16(gB1[s], &sB1[0][offB[s]]);
#pragma unroll
    for (int s = 0; s < 2; ++s) async16(gB3[s], &sB3[0][offB[s]]);
    asm volatile("s_waitcnt vmcnt(2)" ::: "memory");   // A + B1 landed (B3 covered in P1)
    __builtin_amdgcn_s_barrier();
    FENCE();

    for (int t = 0; t < D_MODEL / 64; ++t) {
        int p = t & 1;
        int k1 = (t + 1) * 64;
        bool pf = (t < D_MODEL / 64 - 1);
        bf16x8 a[4], u[4];

        // ---- P1: a(kk0), u1(kk0); stage A01(t+1); vmcnt(2) covers t's B3 ----
#pragma unroll
        for (int i = 0; i < 4; ++i) a[i] = *(const bf16x8*)(&sA[p][fA[i]]);
#pragma unroll
        for (int j = 0; j < 4; ++j) u[j] = *(const bf16x8*)(&sB1[p][fB[j]]);
        if (pf) {
            async16(gA[0] + k1, &sA[p ^ 1][offA[0]]);
            async16(gA[1] + k1, &sA[p ^ 1][offA[1]]);
            asm volatile("s_waitcnt vmcnt(2)" ::: "memory");
        } else {
            asm volatile("s_waitcnt vmcnt(0)" ::: "memory");
        }
        __builtin_amdgcn_s_barrier();
        FENCE();
        __builtin_amdgcn_s_setprio(1);
#pragma unroll
        for (int i = 0; i < 4; ++i)
#pragma unroll
            for (int j = 0; j < 4; ++j)
                acc1[i][j] = __builtin_amdgcn_mfma_f32_16x16x32_bf16(a[i], u[j], acc1[i][j], 0, 0, 0);
        __builtin_amdgcn_s_setprio(0);
        FENCE();
        __builtin_amdgcn_s_barrier();
        FENCE();

        // ---- P2: u3(kk0), reuse a; stage A23(t+1) ----
#pragma unroll
        for (int j = 0; j < 4; ++j) u[j] = *(const bf16x8*)(&sB3[p][fB[j]]);
        if (pf) {
            async16(gA[2] + k1, &sA[p ^ 1][offA[2]]);
            async16(gA[3] + k1, &sA[p ^ 1][offA[3]]);
        }
        __builtin_amdgcn_s_barrier();
        FENCE();
        __builtin_amdgcn_s_setprio(1);
#pragma unroll
        for (int i = 0; i < 4; ++i)
#pragma unroll
            for (int j = 0; j < 4; ++j)
                acc3[i][j] = __builtin_amdgcn_mfma_f32_16x16x32_bf16(a[i], u[j], acc3[i][j], 0, 0, 0);
        __builtin_amdgcn_s_setprio(0);
        FENCE();
        __builtin_amdgcn_s_barrier();
        FENCE();

        // ---- P3: a(kk1), u1(kk1); stage B1(t+1) ----
#pragma unroll
        for (int i = 0; i < 4; ++i) a[i] = *(const bf16x8*)(&sA[p][fA[i] ^ 32]);
#pragma unroll
        for (int j = 0; j < 4; ++j) u[j] = *(const bf16x8*)(&sB1[p][fB[j] ^ 32]);
        if (pf) {
            async16(gB1[0] + k1, &sB1[p ^ 1][offB[0]]);
            async16(gB1[1] + k1, &sB1[p ^ 1][offB[1]]);
        }
        __builtin_amdgcn_s_barrier();
        FENCE();
        __builtin_amdgcn_s_setprio(1);
#pragma unroll
        for (int i = 0; i < 4; ++i)
#pragma unroll
            for (int j = 0; j < 4; ++j)
                acc1[i][j] = __builtin_amdgcn_mfma_f32_16x16x32_bf16(a[i], u[j], acc1[i][j], 0, 0, 0);
        __builtin_amdgcn_s_setprio(0);
        FENCE();
        __builtin_amdgcn_s_barrier();
        FENCE();

        // ---- P4: u3(kk1); stage B3(t+1); vmcnt(2) covers t+1's A+B1 ----
#pragma unroll
        for (int j = 0; j < 4; ++j) u[j] = *(const bf16x8*)(&sB3[p][fB[j] ^ 32]);
        if (pf) {
            async16(gB3[0] + k1, &sB3[p ^ 1][offB[0]]);
            async16(gB3[1] + k1, &sB3[p ^ 1][offB[1]]);
            asm volatile("s_waitcnt vmcnt(2)" ::: "memory");
        }
        __builtin_amdgcn_s_barrier();
        FENCE();
        __builtin_amdgcn_s_setprio(1);
#pragma unroll
        for (int i = 0; i < 4; ++i)
#pragma unroll
            for (int j = 0; j < 4; ++j)
                acc3[i][j] = __builtin_amdgcn_mfma_f32_16x16x32_bf16(a[i], u[j], acc3[i][j], 0, 0, 0);
        __builtin_amdgcn_s_setprio(0);
        FENCE();
        __builtin_amdgcn_s_barrier();
        FENCE();
    }

#pragma unroll
    for (int j = 0; j < 4; ++j) {
        int n = tile_n + wn + j * 16 + col;
        float bias1 = b1[e * D_FF + n];
        float bias3 = b3[e * D_FF + n];
#pragma unroll
        for (int i = 0; i < 4; ++i) {
            int rbase = wm + i * 16 + quad * 4;
#pragma unroll
            for (int r = 0; r < 4; ++r) {
                int row = rbase + r;
                if (row < rows_left) {
                    float h1 = acc1[i][j][r] + bias1;
                    float h3 = acc3[i][j][r] + bias3;
                    float s = h1 / (1.f + __expf(-h1));   // silu
                    H[(size_t)(row0 + row) * D_FF + n] = f2bf(s * h3);
                }
            }
        }
    }
}

// ---------------- grouped GEMM2: Y[bucket_row] = H @ W2 + b2 (plain stores) ----------------
__global__ __launch_bounds__(512, 2) void k_gemm2(
    const ushort_t* __restrict__ H, const ushort_t* __restrict__ W2t,
    const float* __restrict__ b2,
    const int* __restrict__ counts, const int* __restrict__ offsets,
    float* __restrict__ Y)
{
    __shared__ __align__(16) ushort_t sA[3][256 * 64];   // 96 KB, triple-buffered
    __shared__ __align__(16) ushort_t sB[3][128 * 64];   // 48 KB

    int bx = blockIdx.x;
    int lx = (bx & 7) * 5 + (bx >> 3);

    int tm = lx, e = 0, cnt = 0;
    for (; e < NE; ++e) {
        cnt = counts[e];
        int nt = (cnt + 255) >> 8;
        if (tm < nt) break;
        tm -= nt;
    }
    if (e >= NE) return;
    int row0 = offsets[e] + tm * 256;
    int rows_left = cnt - tm * 256;

    int tile_n = blockIdx.y * 128;
    int tid = threadIdx.x, wave = tid >> 6, lane = tid & 63;
    int wm = (wave >> 1) * 64, wn = (wave & 1) * 64;
    int col = lane & 15, quad = lane >> 4;

    const ushort_t* W2e = W2t + (size_t)e * D_MODEL * D_FF;

    const ushort_t* gA[4]; const ushort_t* gB[2];
    unsigned offA[4], offB[2];
#pragma unroll
    for (int s = 0; s < 4; ++s) {
        int q = (wave * 4 + s) * 64 + lane;
        int r = q >> 3;
        int cg = ((q & 7) ^ (r & 7)) * 8;
        gA[s] = H + (size_t)(row0 + r) * D_FF + cg;
        offA[s] = (unsigned)(wave * 4 + s) * 512;
    }
#pragma unroll
    for (int s = 0; s < 2; ++s) {
        int q = (wave * 2 + s) * 64 + lane;
        int r = q >> 3;
        int cg = ((q & 7) ^ (r & 7)) * 8;
        gB[s] = W2e + (size_t)(tile_n + r) * D_FF + cg;
        offB[s] = (unsigned)(wave * 2 + s) * 512;
    }

    int swz = (quad ^ (col & 7)) * 8;
    unsigned fA[4], fB[4];
#pragma unroll
    for (int i = 0; i < 4; ++i) {
        fA[i] = (unsigned)(wm + i * 16 + col) * 64 + swz;
        fB[i] = (unsigned)(wn + i * 16 + col) * 64 + swz;
    }

    f32x4 acc[4][4];
#pragma unroll
    for (int i = 0; i < 4; ++i)
#pragma unroll
        for (int j = 0; j < 4; ++j) acc[i][j] = (f32x4){0.f, 0.f, 0.f, 0.f};

    // prologue: tiles 0 and 1 -> bufs 0,1 (6 units each)
#pragma unroll
    for (int s = 0; s < 4; ++s) async16(gA[s], &sA[0][offA[s]]);
#pragma unroll
    for (int s = 0; s < 2; ++s) async16(gB[s], &sB[0][offB[s]]);
#pragma unroll
    for (int s = 0; s < 4; ++s) async16(gA[s] + 64, &sA[1][offA[s]]);
#pragma unroll
    for (int s = 0; s < 2; ++s) async16(gB[s] + 64, &sB[1][offB[s]]);
    asm volatile("s_waitcnt vmcnt(6)" ::: "memory");   // tile 0 landed; tile 1 in flight
    __builtin_amdgcn_s_barrier();
    FENCE();

    int pb = 0;
    for (int t = 0; t < D_FF / 64; ++t) {
        int pn = (pb == 0) ? 2 : pb - 1;    // (t+2) % 3
        int k2 = (t + 2) * 64;
        bool pf = (t < D_FF / 64 - 2);
        bf16x8 a[4], b[4];

        // ---- P1: kk0; stage A012(t+2) ----
#pragma unroll
        for (int i = 0; i < 4; ++i) a[i] = *(const bf16x8*)(&sA[pb][fA[i]]);
#pragma unroll
        for (int j = 0; j < 4; ++j) b[j] = *(const bf16x8*)(&sB[pb][fB[j]]);
        if (pf) {
            async16(gA[0] + k2, &sA[pn][offA[0]]);
            async16(gA[1] + k2, &sA[pn][offA[1]]);
            async16(gA[2] + k2, &sA[pn][offA[2]]);
        }
        __builtin_amdgcn_s_barrier();
        FENCE();
        __builtin_amdgcn_s_setprio(1);
#pragma unroll
        for (int i = 0; i < 4; ++i)
#pragma unroll
            for (int j = 0; j < 4; ++j)
                acc[i][j] = __builtin_amdgcn_mfma_f32_16x16x32_bf16(a[i], b[j], acc[i][j], 0, 0, 0);
        __builtin_amdgcn_s_setprio(0);
        FENCE();
        __builtin_amdgcn_s_barrier();
        FENCE();

        // ---- P2: kk1; stage A3+B01(t+2); vmcnt(6) covers t+1's 6 units ----
#pragma unroll
        for (int i = 0; i < 4; ++i) a[i] = *(const bf16x8*)(&sA[pb][fA[i] ^ 32]);
#pragma unroll
        for (int j = 0; j < 4; ++j) b[j] = *(const bf16x8*)(&sB[pb][fB[j] ^ 32]);
        if (pf) {
            async16(gA[3] + k2, &sA[pn][offA[3]]);
            async16(gB[0] + k2, &sB[pn][offB[0]]);
            async16(gB[1] + k2, &sB[pn][offB[1]]);
            asm volatile("s_waitcnt vmcnt(6)" ::: "memory");
        } else {
            asm volatile("s_waitcnt vmcnt(0)" ::: "memory");
        }
        __builtin_amdgcn_s_barrier();
        FENCE();
        __builtin_amdgcn_s_setprio(1);
#pragma unroll
        for (int i = 0; i < 4; ++i)
#pragma unroll
            for (int j = 0; j < 4; ++j)
                acc[i][j] = __builtin_amdgcn_mfma_f32_16x16x32_bf16(a[i], b[j], acc[i][j], 0, 0, 0);
        __builtin_amdgcn_s_setprio(0);
        FENCE();
        __builtin_amdgcn_s_barrier();
        FENCE();

        pb = (pb == 2) ? 0 : pb + 1;
    }

    float bias[4];
#pragma unroll
    for (int j = 0; j < 4; ++j) bias[j] = b2[e * D_MODEL + tile_n + wn + j * 16 + col];

#pragma unroll
    for (int i = 0; i < 4; ++i) {
        int rbase = wm + i * 16 + quad * 4;
#pragma unroll
        for (int r = 0; r < 4; ++r) {
            int row = rbase + r;
            if (row < rows_left) {
                float* yrow = Y + (size_t)(row0 + row) * D_MODEL + tile_n + wn + col;
#pragma unroll
                for (int j = 0; j < 4; ++j)
                    yrow[j * 16] = acc[i][j][r] + bias[j];
            }
        }
    }
}

// ---------------- combine: out[t] = w0*Y[p0] + w1*Y[p1] ----------------
__global__ __launch_bounds__(256) void k_combine(
    const float* __restrict__ Y, const int* __restrict__ pos,
    const float* __restrict__ topw, float* __restrict__ out)
{
    int t = blockIdx.x, c = threadIdx.x;
    int p0 = pos[t * 2 + 0], p1 = pos[t * 2 + 1];
    float w0 = topw[t * 2 + 0], w1 = topw[t * 2 + 1];
    float4 y0 = ((const float4*)(Y + (size_t)p0 * D_MODEL))[c];
    float4 y1 = ((const float4*)(Y + (size_t)p1 * D_MODEL))[c];
    float4 o;
    o.x = w0 * y0.x + w1 * y1.x;
    o.y = w0 * y0.y + w1 * y1.y;
    o.z = w0 * y0.z + w1 * y1.z;
    o.w = w0 * y0.w + w1 * y1.w;
    ((float4*)(out + (size_t)t * D_MODEL))[c] = o;
}

extern "C" void kernel_launch(void* const* d_in, const int* in_sizes, int n_in,
                              void* d_out, int out_size, void* d_ws, size_t ws_size,
                              hipStream_t stream)
{
    const float* x  = (const float*)d_in[0];
    const float* Wg = (const float*)d_in[1];
    const float* bg = (const float*)d_in[2];
    const float* W1 = (const float*)d_in[3];
    const float* b1 = (const float*)d_in[4];
    const float* W3 = (const float*)d_in[5];
    const float* b3 = (const float*)d_in[6];
    const float* W2 = (const float*)d_in[7];
    const float* b2 = (const float*)d_in[8];
    float* out = (float*)d_out;

    char* ws = (char*)d_ws;
    int*   counts  = (int*)(ws + 0);
    int*   cursors = (int*)(ws + 32);
    int*   offsets = (int*)(ws + 64);
    int*   topi    = (int*)(ws + 256);
    float* topw    = (float*)(ws + 256 + 32768);
    int*   btok    = (int*)(ws + 256 + 65536);
    float* bw      = (float*)(ws + 256 + 98304);
    char* p = ws + 131328;
    ushort_t* Xg  = (ushort_t*)p;  p += (size_t)R_TOT * D_MODEL * 2;      // 16.78 MB
    ushort_t* Hb  = (ushort_t*)p;  p += (size_t)R_TOT * D_FF * 2;         // 67.1 MB
    ushort_t* W1t = (ushort_t*)p;  p += (size_t)NE * D_FF * D_MODEL * 2;  // 67.1 MB
    ushort_t* W3t = (ushort_t*)p;  p += (size_t)NE * D_FF * D_MODEL * 2;  // 67.1 MB
    ushort_t* W2t = (ushort_t*)p;                                          // 67.1 MB
    // Y overlays W1t (dead after k_gemm1): 8192*1024*4 = 33.5 MB <= 67.1 MB
    float* Y = (float*)W1t;

    hipMemsetAsync(ws, 0, 64, stream);                       // counts + cursors

    k_gate<<<dim3(T_TOK / 4), dim3(256), 0, stream>>>(x, Wg, bg, topi, topw, counts);
    k_scan<<<dim3(1), dim3(64), 0, stream>>>(counts, offsets, cursors);
    k_scatter<<<dim3(T_TOK / 256), dim3(256), 0, stream>>>(topi, topw, cursors, btok, bw);
    k_gather<<<dim3(R_TOT), dim3(256), 0, stream>>>(x, btok, Xg);
    k_transpose<<<dim3(D_FF / 64, D_MODEL / 64, NE), dim3(256), 0, stream>>>(W1, W1t, D_MODEL, D_FF);
    k_transpose<<<dim3(D_FF / 64, D_MODEL / 64, NE), dim3(256), 0, stream>>>(W3, W3t, D_MODEL, D_FF);
    k_transpose<<<dim3(D_MODEL / 64, D_FF / 64, NE), dim3(256), 0, stream>>>(W2, W2t, D_FF, D_MODEL);
    // grid.x = 40 = max row-tiles (sum ceil(cnt_e/256) <= 40) and = 8 XCDs * 5 for the swizzle
    k_gemm1<<<dim3(40, D_FF / 128), dim3(512), 0, stream>>>(Xg, W1t, W3t, b1, b3, counts, offsets, Hb);
    k_gemm2<<<dim3(40, D_MODEL / 128), dim3(512), 0, stream>>>(Hb, W2t, b2, counts, offsets, Y);
    k_combine<<<dim3(T_TOK), dim3(256), 0, stream>>>(Y, topi, topw, out);
}